// Round 1
// baseline (4735.554 us; speedup 1.0000x reference)
//
#include <hip/hip_runtime.h>

// StreamingClusterCompactor: T=32768, H=32, D=128, G=8, hpg=4, M=512
#define T_TOK 32768
#define NH    32
#define DIM   128
#define NG    8
#define HPG   4
#define NM    512
#define TB    32   // tokens per block

// ws layout (floats): Kacc [NG*NM*DIM], Vacc [NG*NM*DIM], Z [NG*NM]
#define KACC_OFF 0
#define VACC_OFF (NG*NM*DIM)
#define Z_OFF    (2*NG*NM*DIM)
#define WS_FLOATS (2*NG*NM*DIM + NG*NM)

// Fused: head-mean -> fp32 score GEMM vs anchors -> argmax -> atomic scatter-add.
// Block: 256 threads. blockIdx.x = token chunk (TB tokens), blockIdx.y = group.
// Thread tile: 4 tokens x 16 anchors (m = ag + 32*q), fp32 acc in VGPRs.
__global__ __launch_bounds__(256) void route_accum(
    const float* __restrict__ K_cold, const float* __restrict__ V_cold,
    const float* __restrict__ anchors, float* __restrict__ ws)
{
  __shared__ float sKg[DIM * 33];   // Kg transposed: [d][token], stride 33 (conflict-free)
  __shared__ float sA[8 * 513];     // anchor k-slice: [kk][m], stride 513 (conflict-free)
  __shared__ int   sBest[TB];

  const int tid = threadIdx.x;
  const int t0  = blockIdx.x * TB;
  const int g   = blockIdx.y;
  const int tg  = tid >> 5;     // 0..7  (token group: 4 tokens each)
  const int ag  = tid & 31;     // 0..31 (anchor lane)

  // ---- Phase A: Kg head-means into LDS (transposed [d][t]) ----
  {
    const int d  = tid & 127;
    const int th = tid >> 7;    // 0 or 1
    for (int it = 0; it < TB; it += 2) {
      const int tk = it + th;
      const float* kp = K_cold + ((size_t)(t0 + tk) * NH + g * HPG) * DIM + d;
      sKg[d * 33 + tk] = 0.25f * (kp[0] + kp[DIM] + kp[2 * DIM] + kp[3 * DIM]);
    }
  }

  // ---- Phase B: fp32 score GEMM (scale skipped: argmax invariant) ----
  float acc[4][16];
  #pragma unroll
  for (int i = 0; i < 4; ++i)
    #pragma unroll
    for (int q = 0; q < 16; ++q) acc[i][q] = 0.f;

  const float* Ag = anchors + (size_t)g * NM * DIM;
  for (int kc = 0; kc < DIM; kc += 8) {
    __syncthreads();  // also covers Phase A on first iteration
    // stage sA[kk][m], kk in [0,8): 4096 elements, 16 per thread
    #pragma unroll
    for (int r = 0; r < 16; ++r) {
      const int l  = r * 256 + tid;
      const int m  = l >> 3;
      const int kk = l & 7;
      sA[kk * 513 + m] = Ag[(size_t)m * DIM + kc + kk];
    }
    __syncthreads();
    #pragma unroll
    for (int kk = 0; kk < 8; ++kk) {
      float kv[4];
      #pragma unroll
      for (int i = 0; i < 4; ++i) kv[i] = sKg[(kc + kk) * 33 + tg * 4 + i];  // broadcast
      #pragma unroll
      for (int q = 0; q < 16; ++q) {
        const float a = sA[kk * 513 + ag + 32 * q];
        #pragma unroll
        for (int i = 0; i < 4; ++i) acc[i][q] = fmaf(kv[i], a, acc[i][q]);
      }
    }
  }

  // ---- Phase C: per-token argmax (lowest index wins ties, matching jnp.argmax) ----
  #pragma unroll
  for (int i = 0; i < 4; ++i) {
    float bv = acc[i][0];
    int   bm = ag;
    #pragma unroll
    for (int q = 1; q < 16; ++q) {
      const int m = ag + 32 * q;   // ascending m: strict > keeps lowest index
      if (acc[i][q] > bv) { bv = acc[i][q]; bm = m; }
    }
    for (int off = 16; off >= 1; off >>= 1) {   // stays within 32-lane ag groups
      const float ov = __shfl_xor(bv, off);
      const int   om = __shfl_xor(bm, off);
      if (ov > bv || (ov == bv && om < bm)) { bv = ov; bm = om; }
    }
    if (ag == 0) sBest[tg * 4 + i] = bm;
  }
  __syncthreads();

  // ---- Phase D: atomic scatter-add of Kg (from LDS) and Vg (fresh from HBM) ----
  float* Kacc = ws + KACC_OFF;
  float* Vacc = ws + VACC_OFF;
  float* Zacc = ws + Z_OFF;
  {
    const int tk = tid >> 3;   // 0..31
    const int dq = tid & 7;    // 0..7
    const int m  = sBest[tk];
    float* ka = Kacc + ((size_t)g * NM + m) * DIM;
    float* va = Vacc + ((size_t)g * NM + m) * DIM;
    const float* vp = V_cold + ((size_t)(t0 + tk) * NH + g * HPG) * DIM;
    #pragma unroll
    for (int j = 0; j < 16; ++j) {
      const int d = dq * 16 + j;   // each lane streams one contiguous 64B line per head row
      unsafeAtomicAdd(&ka[d], sKg[d * 33 + tk]);
      const float vs = vp[d] + vp[DIM + d] + vp[2 * DIM + d] + vp[3 * DIM + d];
      unsafeAtomicAdd(&va[d], 0.25f * vs);
    }
    if (tid < TB) unsafeAtomicAdd(&Zacc[(size_t)g * NM + sBest[tid]], 1.0f);
  }
}

// Normalize + broadcast group accumulators to (M, H, D) for K and V halves of d_out.
__global__ __launch_bounds__(256) void finalize(const float* __restrict__ ws,
                                                float* __restrict__ out)
{
  const size_t idx = (size_t)blockIdx.x * 256 + threadIdx.x;  // over M*H*D
  const int d = (int)(idx & 127);
  const int h = (int)((idx >> 7) & 31);
  const int m = (int)(idx >> 12);
  const int g = h >> 2;
  const float z = fmaxf(ws[Z_OFF + g * NM + m], 1e-8f);
  const size_t src = ((size_t)g * NM + m) * DIM + d;
  out[idx] = ws[KACC_OFF + src] / z;
  out[idx + (size_t)NM * NH * DIM] = ws[VACC_OFF + src] / z;
}

extern "C" void kernel_launch(void* const* d_in, const int* in_sizes, int n_in,
                              void* d_out, int out_size, void* d_ws, size_t ws_size,
                              hipStream_t stream)
{
  const float* K = (const float*)d_in[0];
  const float* V = (const float*)d_in[1];
  const float* A = (const float*)d_in[2];
  float* ws = (float*)d_ws;

  hipMemsetAsync(d_ws, 0, (size_t)WS_FLOATS * sizeof(float), stream);

  dim3 grid(T_TOK / TB, NG);
  route_accum<<<grid, 256, 0, stream>>>(K, V, A, ws);

  finalize<<<(NM * NH * DIM) / 256, 256, 0, stream>>>(ws, (float*)d_out);
}

// Round 2
// 2323.419 us; speedup vs baseline: 2.0382x; 2.0382x over previous
//
#include <hip/hip_runtime.h>

// StreamingClusterCompactor: T=32768, H=32, D=128, G=8, hpg=4, M=512
#define T_TOK 32768
#define NH    32
#define DIM   128
#define NG    8
#define HPG   4
#define NM    512
#define TB    32          // tokens per route block
#define NSEG  (NG*NM)     // 4096 segments

// ws layout in 4-byte units:
#define CNT_OFF  0                       // int[4096]  histogram
#define CUR_OFF  4096                    // int[4096]  scatter cursors
#define OFS_OFF  8192                    // int[4096]  segment offsets
#define IDX_OFF  12288                   // int[T*G]   top-1 anchor per (g,t)
#define PERM_OFF (12288 + T_TOK*NG)      // int[T*G]   token permutation (CSR)
#define AT_OFF   (PERM_OFF + T_TOK*NG)   // float[G*D*M] transposed anchors

// ---- Kernel 0: transpose anchors A[g][m][d] -> At[g][d][m] for coalesced staging ----
__global__ __launch_bounds__(256) void transpose_anchors(const float* __restrict__ A,
                                                         float* __restrict__ At)
{
  __shared__ float tile[32][33];
  const int g  = blockIdx.z;
  const int m0 = blockIdx.y * 32;
  const int d0 = blockIdx.x * 32;
  const int tx = threadIdx.x & 31;
  const int ty = threadIdx.x >> 5;   // 0..7
  #pragma unroll
  for (int k = 0; k < 32; k += 8)
    tile[ty + k][tx] = A[((size_t)g * NM + m0 + ty + k) * DIM + d0 + tx];
  __syncthreads();
  #pragma unroll
  for (int k = 0; k < 32; k += 8)
    At[((size_t)g * DIM + d0 + ty + k) * NM + m0 + tx] = tile[tx][ty + k];
}

// ---- Kernel 1: head-mean -> fp32 score GEMM -> argmax -> idx + histogram ----
__global__ __launch_bounds__(256, 4) void route(
    const float* __restrict__ K_cold, const float* __restrict__ At,
    int* __restrict__ wsi)
{
  __shared__ float sKg[DIM * 33];   // Kg^T [d][t], stride 33 (conflict-free)
  __shared__ float sA[8 * 513];     // anchor k-slice [kk][m], stride 513
  __shared__ int   sBest[TB];

  const int tid = threadIdx.x;
  const int t0  = blockIdx.x * TB;
  const int g   = blockIdx.y;
  const int tg  = tid >> 5;     // 0..7
  const int ag  = tid & 31;     // 0..31

  // Phase A: per-group head means of K into LDS (transposed)
  {
    const int d  = tid & 127;
    const int th = tid >> 7;
    for (int it = 0; it < TB; it += 2) {
      const int tk = it + th;
      const float* kp = K_cold + ((size_t)(t0 + tk) * NH + g * HPG) * DIM + d;
      sKg[d * 33 + tk] = 0.25f * (kp[0] + kp[DIM] + kp[2 * DIM] + kp[3 * DIM]);
    }
  }

  // Phase B: fp32 scores (scale skipped: argmax-invariant)
  float acc[4][16];
  #pragma unroll
  for (int i = 0; i < 4; ++i)
    #pragma unroll
    for (int q = 0; q < 16; ++q) acc[i][q] = 0.f;

  const float* Atg = At + (size_t)g * DIM * NM;
  for (int kc = 0; kc < DIM; kc += 8) {
    __syncthreads();
    #pragma unroll
    for (int r = 0; r < 16; ++r) {          // stage sA: fully coalesced from At
      const int l  = r * 256 + tid;
      const int kk = l >> 9;
      const int m  = l & 511;
      sA[kk * 513 + m] = Atg[(size_t)(kc + kk) * NM + m];
    }
    __syncthreads();
    #pragma unroll
    for (int kk = 0; kk < 8; ++kk) {
      float kv[4];
      #pragma unroll
      for (int i = 0; i < 4; ++i) kv[i] = sKg[(kc + kk) * 33 + tg * 4 + i];
      #pragma unroll
      for (int q = 0; q < 16; ++q) {
        const float a = sA[kk * 513 + ag + 32 * q];
        #pragma unroll
        for (int i = 0; i < 4; ++i) acc[i][q] = fmaf(kv[i], a, acc[i][q]);
      }
    }
  }

  // Phase C: per-token argmax (lowest index wins ties)
  #pragma unroll
  for (int i = 0; i < 4; ++i) {
    float bv = acc[i][0];
    int   bm = ag;
    #pragma unroll
    for (int q = 1; q < 16; ++q) {
      const int m = ag + 32 * q;
      if (acc[i][q] > bv) { bv = acc[i][q]; bm = m; }
    }
    for (int off = 16; off >= 1; off >>= 1) {
      const float ov = __shfl_xor(bv, off);
      const int   om = __shfl_xor(bm, off);
      if (ov > bv || (ov == bv && om < bm)) { bv = ov; bm = om; }
    }
    if (ag == 0) sBest[tg * 4 + i] = bm;
  }
  __syncthreads();

  // Phase D: write idx + histogram (int atomics only)
  if (tid < TB) {
    const int m = sBest[tid];
    wsi[IDX_OFF + g * T_TOK + t0 + tid] = m;
    atomicAdd(&wsi[CNT_OFF + g * NM + m], 1);
  }
}

// ---- Kernel 2: exclusive prefix sum over 4096 counts -> offsets + cursors ----
__global__ __launch_bounds__(1024) void scan_kernel(int* __restrict__ wsi)
{
  __shared__ int sdata[1024];
  const int tid = threadIdx.x;
  int c[4], s = 0;
  #pragma unroll
  for (int j = 0; j < 4; ++j) { c[j] = wsi[CNT_OFF + tid * 4 + j]; s += c[j]; }
  sdata[tid] = s;
  __syncthreads();
  for (int off = 1; off < 1024; off <<= 1) {
    const int v = (tid >= off) ? sdata[tid - off] : 0;
    __syncthreads();
    sdata[tid] += v;
    __syncthreads();
  }
  int base = sdata[tid] - s;   // exclusive
  #pragma unroll
  for (int j = 0; j < 4; ++j) {
    wsi[OFS_OFF + tid * 4 + j] = base;
    wsi[CUR_OFF + tid * 4 + j] = base;
    base += c[j];
  }
}

// ---- Kernel 3: build CSR permutation ----
__global__ __launch_bounds__(256) void scatter_kernel(int* __restrict__ wsi)
{
  const int i = blockIdx.x * 256 + threadIdx.x;   // i = g*T + t
  const int g = i >> 15;
  const int t = i & (T_TOK - 1);
  const int m = wsi[IDX_OFF + i];
  const int slot = atomicAdd(&wsi[CUR_OFF + g * NM + m], 1);
  wsi[PERM_OFF + slot] = t;
}

// ---- Kernel 4: per-(g,m) gather-reduce of K and V, normalize, broadcast to heads ----
__global__ __launch_bounds__(256) void reduce_kernel(
    const float* __restrict__ K_cold, const float* __restrict__ V_cold,
    const int* __restrict__ wsi, float* __restrict__ out)
{
  __shared__ float4 sred[256];
  const int gm  = blockIdx.x;
  const int g   = gm >> 9;
  const int m   = gm & (NM - 1);
  const int n   = wsi[CNT_OFF + gm];
  const int o   = wsi[OFS_OFF + gm];
  const int tid = threadIdx.x;
  const int half = tid >> 7;          // 0: K, 1: V
  const int l    = tid & 127;         // element quad e = 4l of the (4h x 128d) token block
  const float* src = half ? V_cold : K_cold;
  const int* perm = wsi + PERM_OFF + o;

  float4 acc = {0.f, 0.f, 0.f, 0.f};
  int j = 0;
  for (; j + 1 < n; j += 2) {
    const int t0 = perm[j], t1 = perm[j + 1];
    const float4 v0 = *(const float4*)(src + ((size_t)t0 * NH + g * HPG) * DIM + l * 4);
    const float4 v1 = *(const float4*)(src + ((size_t)t1 * NH + g * HPG) * DIM + l * 4);
    acc.x += v0.x + v1.x; acc.y += v0.y + v1.y;
    acc.z += v0.z + v1.z; acc.w += v0.w + v1.w;
  }
  if (j < n) {
    const int t = perm[j];
    const float4 v = *(const float4*)(src + ((size_t)t * NH + g * HPG) * DIM + l * 4);
    acc.x += v.x; acc.y += v.y; acc.z += v.z; acc.w += v.w;
  }

  sred[half * 128 + l] = acc;          // l = h*32 + dq (h=l>>5, d=4*(l&31))
  __syncthreads();

  if (tid < 64) {
    const int kv = tid >> 5, dq = tid & 31;
    float4 s = {0.f, 0.f, 0.f, 0.f};
    #pragma unroll
    for (int h = 0; h < 4; ++h) {
      const float4 v = sred[kv * 128 + h * 32 + dq];
      s.x += v.x; s.y += v.y; s.z += v.z; s.w += v.w;
    }
    const float inv = (n > 0) ? (0.25f / (float)n) : 0.f;   // head-mean / count
    s.x *= inv; s.y *= inv; s.z *= inv; s.w *= inv;
    float* ob = out + (size_t)kv * NM * NH * DIM + ((size_t)m * NH + g * HPG) * DIM + dq * 4;
    #pragma unroll
    for (int h = 0; h < 4; ++h) *((float4*)(ob + h * DIM)) = s;
  }
}

extern "C" void kernel_launch(void* const* d_in, const int* in_sizes, int n_in,
                              void* d_out, int out_size, void* d_ws, size_t ws_size,
                              hipStream_t stream)
{
  const float* K = (const float*)d_in[0];
  const float* V = (const float*)d_in[1];
  const float* A = (const float*)d_in[2];
  int*   wsi = (int*)d_ws;
  float* At  = (float*)d_ws + AT_OFF;

  hipMemsetAsync(wsi + CNT_OFF, 0, NSEG * sizeof(int), stream);

  transpose_anchors<<<dim3(DIM / 32, NM / 32, NG), 256, 0, stream>>>(A, At);
  route<<<dim3(T_TOK / TB, NG), 256, 0, stream>>>(K, At, wsi);
  scan_kernel<<<1, 1024, 0, stream>>>(wsi);
  scatter_kernel<<<(T_TOK * NG) / 256, 256, 0, stream>>>(wsi);
  reduce_kernel<<<NSEG, 256, 0, stream>>>(K, V, wsi, (float*)d_out);
}